// Round 11
// baseline (79.549 us; speedup 1.0000x reference)
//
#include <hip/hip_runtime.h>
#include <hip/hip_bf16.h>
#include <math.h>

#define NPTS 4096
#define SDIM 128
#define NV 6
#define KTOP 5
#define IMG_ELEMS (NV * SDIM * SDIM * 3)   // 294912

// fp32(0.01*0.01) = 9.99999975e-05 == fp32 literal 1e-4f
#define R2F 1e-4f
#define RMARG 0.0102f        // conservative candidate margin (> radius 0.01)

#define RB 32                // region: 32x32 px, 1024 threads = 1 thread/pixel
#define NBLK (NV * 16)       // 16 regions/view -> 96 blocks (all concurrent)
#define NCX 4                // cells: 8 px wide x 4 px tall -> 4 cols x 8 rows
#define NCY 8
#define NCELL 32
#define CAPS 126             // worst-cell mean ~87, 4.2 sigma headroom
// LDS: 32*127*16 + 128 = 65152 B <= 64 KB block limit

struct CamParams { float R[NV][9]; float T[NV][3]; };

__device__ __forceinline__ float sigmoidf_fast(float x) {
  return __fdividef(1.0f, 1.0f + __expf(-x));
}

__device__ __forceinline__ void process_cand(
    float4 P, float xf, float yf,
    float zk[KTOP], float wk[KTOP], float ck[KTOP]) {
  float dx = xf - P.x;
  float dy = yf - P.y;
  float d2 = dx * dx + dy * dy;
  if (d2 < R2F) {                     // strict, matches ref hit = d2 < R2
    float wgt = 1.0f - d2 / R2F;      // exact ref arithmetic
    float z = P.z;
    if (z < zk[KTOP - 1]) {
      zk[KTOP - 1] = z; wk[KTOP - 1] = wgt; ck[KTOP - 1] = P.w;
#pragma unroll
      for (int k = KTOP - 1; k > 0; k--) {
        if (zk[k] < zk[k - 1]) {      // strict: stable on (measure-zero) ties
          float tz = zk[k]; zk[k] = zk[k - 1]; zk[k - 1] = tz;
          float tw = wk[k]; wk[k] = wk[k - 1]; wk[k - 1] = tw;
          float tc = ck[k]; ck[k] = ck[k - 1]; ck[k - 1] = tc;
        }
      }
    }
  }
}

// ==== fused: vec4 transform (4 pts/thread) + per-cell LDS bin + top-5 ====
__global__ __launch_bounds__(1024) void fused_render_kernel(
    const float4* __restrict__ pcd4,     // [3072]
    const float4* __restrict__ add0_4,   // [1024]
    const float4* __restrict__ add1_4,   // [1024]
    float* __restrict__ out,             // images [6,128,128,3]
    float4* __restrict__ out_colors4,    // colors [1024 float4]
    CamParams cams) {
  int b = blockIdx.x;
  int v = b >> 4;                      // 16 blocks per view
  int t = b & 15;
  int ty = t >> 2, tx = t & 3;         // 4x4 regions of 32x32 px
  int tid = threadIdx.x;
  int row = tid >> 5, col = tid & 31;  // 32 rows x 32 cols
  int w0 = tx * RB, h0 = ty * RB;
  int h = h0 + row;
  int w = w0 + col;
  float xf = (float)(127 - 2 * w) * (1.0f / 128.0f);
  float yf = (float)(127 - 2 * h) * (1.0f / 128.0f);

  // region NDC bounds (xf decreasing in w)
  float xhi = (float)(127 - 2 * w0) * (1.0f / 128.0f) + RMARG;
  float xlo = (float)(127 - 2 * (w0 + RB - 1)) * (1.0f / 128.0f) - RMARG;
  float yhi = (float)(127 - 2 * h0) * (1.0f / 128.0f) + RMARG;
  float ylo = (float)(127 - 2 * (h0 + RB - 1)) * (1.0f / 128.0f) - RMARG;

  // stride 127 float4 = 508 dwords: consecutive lists start on banks
  // 0/28/24/20 (disjoint quads) -> conflict-free b128 broadcasts in phase 2.
  __shared__ float4 cand[NCELL][CAPS + 1];
  __shared__ int cnts[NCELL];
  if (tid < NCELL) cnts[tid] = 0;
  __syncthreads();

  const float* Rp = cams.R[v];
  const float* Tp = cams.T[v];
  float R0 = Rp[0], R1 = Rp[1], R2 = Rp[2];
  float R3 = Rp[3], R4 = Rp[4], R5 = Rp[5];
  float R6 = Rp[6], R7 = Rp[7], R8 = Rp[8];
  float T0 = Tp[0], T1 = Tp[1], T2 = Tp[2];

  // ---- phase 1: 5 vec4 loads, transform 4 pts, bin to sub-cells ----
  int g = tid;                         // one 4-point group per thread
  float4 a0 = pcd4[3 * g + 0];
  float4 a1 = pcd4[3 * g + 1];
  float4 a2 = pcd4[3 * g + 2];
  float4 c0 = add0_4[g];
  float4 c1 = add1_4[g];

  float f[12] = {a0.x, a0.y, a0.z, a0.w,
                 a1.x, a1.y, a1.z, a1.w,
                 a2.x, a2.y, a2.z, a2.w};
  float sc[4] = {sigmoidf_fast(c0.x + c1.x),
                 sigmoidf_fast(c0.y + c1.y),
                 sigmoidf_fast(c0.z + c1.z),
                 sigmoidf_fast(c0.w + c1.w)};

  // block 0 (view-0 corner region, light phase 2) emits the colors output
  if (b == 0) out_colors4[g] = make_float4(sc[0], sc[1], sc[2], sc[3]);

#pragma unroll
  for (int j = 0; j < 4; j++) {
    float p0 = f[3 * j + 0], p1 = f[3 * j + 1], p2 = f[3 * j + 2];
    float px = p0 * R0 + p1 * R3 + p2 * R6 + T0;
    float py = p0 * R1 + p1 * R4 + p2 * R7 + T1;
    float pz = p0 * R2 + p1 * R5 + p2 * R8 + T2;
    if (pz > 0.01f && pz < 100.0f &&
        px > xlo && px < xhi && py > ylo && py < yhi) {
      // continuous local pixel span (w = (127-128*px)/2)
      float lwlo = (127.0f - 128.0f * (px + RMARG)) * 0.5f - (float)w0;
      float lwhi = (127.0f - 128.0f * (px - RMARG)) * 0.5f - (float)w0;
      float lhlo = (127.0f - 128.0f * (py + RMARG)) * 0.5f - (float)h0;
      float lhhi = (127.0f - 128.0f * (py - RMARG)) * 0.5f - (float)h0;
      int cxlo = (int)fmaxf(0.0f, floorf(lwlo * 0.125f));   // /8 px
      int cxhi = (int)fminf((float)(NCX - 1), floorf(lwhi * 0.125f));
      int cylo = (int)fmaxf(0.0f, floorf(lhlo * 0.25f));    // /4 px
      int cyhi = (int)fminf((float)(NCY - 1), floorf(lhhi * 0.25f));
      float4 payload = make_float4(px, py, pz, sc[j]);
      for (int cy = cylo; cy <= cyhi; cy++)
        for (int cx = cxlo; cx <= cxhi; cx++) {
          int li = cy * NCX + cx;
          int idx = atomicAdd(&cnts[li], 1);
          if (idx < CAPS) cand[li][idx] = payload;
        }
    }
  }
  __syncthreads();

  // ---- phase 2: scan own 8x4-px cell's list (false positives re-tested) ----
  int li = (row >> 2) * NCX + (col >> 3);
  int n = cnts[li];
  if (n > CAPS) n = CAPS;
  const float4* list = cand[li];

  float zk[KTOP], wk[KTOP], ck[KTOP];
#pragma unroll
  for (int k = 0; k < KTOP; k++) { zk[k] = 1e30f; wk[k] = 0.0f; ck[k] = 0.0f; }

  int j = 0;
  for (; j + 4 <= n; j += 4) {
    float4 P0 = list[j + 0], P1 = list[j + 1];
    float4 P2 = list[j + 2], P3 = list[j + 3];
    process_cand(P0, xf, yf, zk, wk, ck);
    process_cand(P1, xf, yf, zk, wk, ck);
    process_cand(P2, xf, yf, zk, wk, ck);
    process_cand(P3, xf, yf, zk, wk, ck);
  }
  for (; j < n; j++) {
    float4 P = list[j];
    process_cand(P, xf, yf, zk, wk, ck);
  }

  // front-to-back alpha composite; empty slots w=0 are no-ops (matches ref)
  float acc = 0.0f, pre = 1.0f;
#pragma unroll
  for (int k = 0; k < KTOP; k++) {
    acc += wk[k] * pre * ck[k];
    pre *= (1.0f - wk[k]);
  }

  int base = v * (SDIM * SDIM * 3) + (h * SDIM + w) * 3;
  out[base + 0] = acc;
  out[base + 1] = acc;
  out[base + 2] = acc;
}

// ---------------- host: camera R,T from compile-time constants ----------------
static void compute_cams(CamParams* cp) {
  const double views[NV] = {45.0, 90.0, 135.0, 225.0, 270.0, 315.0};
  const double deg = M_PI / 180.0;
  const double elev = 15.0 * deg;
  const double dist = 1.5;
  for (int v = 0; v < NV; v++) {
    double az = views[v] * deg;
    double C[3] = {dist * cos(elev) * sin(az), dist * sin(elev),
                   dist * cos(elev) * cos(az)};
    double n = sqrt(C[0] * C[0] + C[1] * C[1] + C[2] * C[2]);
    double z[3] = {-C[0] / n, -C[1] / n, -C[2] / n};
    double up[3] = {0.0, 1.0, 0.0};
    double x[3] = {up[1] * z[2] - up[2] * z[1],
                   up[2] * z[0] - up[0] * z[2],
                   up[0] * z[1] - up[1] * z[0]};
    double nx = sqrt(x[0] * x[0] + x[1] * x[1] + x[2] * x[2]);
    x[0] /= nx; x[1] /= nx; x[2] /= nx;
    double y[3] = {z[1] * x[2] - z[2] * x[1],
                   z[2] * x[0] - z[0] * x[2],
                   z[0] * x[1] - z[1] * x[0]};
    double ny = sqrt(y[0] * y[0] + y[1] * y[1] + y[2] * y[2]);
    y[0] /= ny; y[1] /= ny; y[2] /= ny;
    double Rm[3][3];  // columns x, y, z
    for (int j = 0; j < 3; j++) { Rm[j][0] = x[j]; Rm[j][1] = y[j]; Rm[j][2] = z[j]; }
    for (int j = 0; j < 3; j++)
      for (int i = 0; i < 3; i++)
        cp->R[v][j * 3 + i] = (float)Rm[j][i];
    for (int i = 0; i < 3; i++)
      cp->T[v][i] = (float)(-(C[0] * Rm[0][i] + C[1] * Rm[1][i] + C[2] * Rm[2][i]));
  }
}

extern "C" void kernel_launch(void* const* d_in, const int* in_sizes, int n_in,
                              void* d_out, int out_size, void* d_ws, size_t ws_size,
                              hipStream_t stream) {
  CamParams cp;
  compute_cams(&cp);

  // Identify inputs by size (robust to ordering): pcd is the unique 3*NPTS
  // array; the two NPTS arrays are symmetric addends (init_colors + displace).
  const float* pcd = nullptr;
  const float* adds[2] = {nullptr, nullptr};
  int na = 0;
  for (int i = 0; i < n_in; i++) {
    if (in_sizes[i] == 3 * NPTS) pcd = (const float*)d_in[i];
    else if (na < 2) adds[na++] = (const float*)d_in[i];
  }
  if (!pcd || na < 2) { pcd = (const float*)d_in[0];
                        adds[0] = (const float*)d_in[1];
                        adds[1] = (const float*)d_in[2]; }

  float* out = (float*)d_out;
  float4* out_colors4 = (float4*)(out + IMG_ELEMS);   // byte offset %16 == 0

  fused_render_kernel<<<NBLK, 1024, 0, stream>>>(
      (const float4*)pcd, (const float4*)adds[0], (const float4*)adds[1],
      out, out_colors4, cp);
}

// Round 12
// 75.406 us; speedup vs baseline: 1.0549x; 1.0549x over previous
//
#include <hip/hip_runtime.h>
#include <hip/hip_bf16.h>
#include <math.h>

#define NPTS 4096
#define SDIM 128
#define NV 6
#define KTOP 5
#define IMG_ELEMS (NV * SDIM * SDIM * 3)   // 294912

// fp32(0.01*0.01) = 9.99999975e-05 == fp32 literal 1e-4f
#define R2F 1e-4f
#define RMARG 0.0102f        // conservative candidate margin (> radius 0.01)

#define RBW 32               // region: 32 px wide x 16 px tall, 512 threads
#define RBH 16
#define NBLK (NV * 32)       // (128/32)*(128/16)=32 regions/view -> 192 blocks
#define NCX 8                // 8x4 sub-cells of 4x4 px
#define NCY 4
#define NCELL 32
#define CAPS 128             // per-cell capacity (worst-cell mean ~50, Poisson-safe)

struct CamParams { float R[NV][9]; float T[NV][3]; };

__device__ __forceinline__ float sigmoidf_fast(float x) {
  return __fdividef(1.0f, 1.0f + __expf(-x));
}

__device__ __forceinline__ void process_cand(
    float4 P, float xf, float yf,
    float zk[KTOP], float wk[KTOP], float ck[KTOP]) {
  float dx = xf - P.x;
  float dy = yf - P.y;
  float d2 = dx * dx + dy * dy;
  if (d2 < R2F) {                     // strict, matches ref hit = d2 < R2
    float wgt = 1.0f - d2 / R2F;      // exact ref arithmetic
    float z = P.z;
    if (z < zk[KTOP - 1]) {
      zk[KTOP - 1] = z; wk[KTOP - 1] = wgt; ck[KTOP - 1] = P.w;
#pragma unroll
      for (int k = KTOP - 1; k > 0; k--) {
        if (zk[k] < zk[k - 1]) {      // strict: stable (lower idx first) on ties
          float tz = zk[k]; zk[k] = zk[k - 1]; zk[k - 1] = tz;
          float tw = wk[k]; wk[k] = wk[k - 1]; wk[k - 1] = tw;
          float tc = ck[k]; ck[k] = ck[k - 1]; ck[k - 1] = tc;
        }
      }
    }
  }
}

// ==== fused: vec4 transform + per-cell LDS bin + per-pixel top-5 + composite ====
__global__ __launch_bounds__(512) void fused_render_kernel(
    const float4* __restrict__ pcd4,     // [3072]
    const float4* __restrict__ add0_4,   // [1024]
    const float4* __restrict__ add1_4,   // [1024]
    float* __restrict__ out,             // images [6,128,128,3]
    float4* __restrict__ out_colors4,    // colors [1024 float4]
    CamParams cams) {
  int b = blockIdx.x;
  int v = b >> 5;                      // 32 blocks per view
  int t = b & 31;
  int ty = t >> 2, tx = t & 3;         // 4 cols x 8 rows of regions
  int tid = threadIdx.x;
  int w0 = tx * RBW, h0 = ty * RBH;    // region origin in pixels
  int row = tid >> 5, col = tid & 31;  // 16 rows x 32 cols
  int h = h0 + row;
  int w = w0 + col;
  float xf = (float)(127 - 2 * w) * (1.0f / 128.0f);
  float yf = (float)(127 - 2 * h) * (1.0f / 128.0f);

  // region NDC bounds (xf decreasing in w)
  float xhi = (float)(127 - 2 * w0) * (1.0f / 128.0f) + RMARG;
  float xlo = (float)(127 - 2 * (w0 + RBW - 1)) * (1.0f / 128.0f) - RMARG;
  float yhi = (float)(127 - 2 * h0) * (1.0f / 128.0f) + RMARG;
  float ylo = (float)(127 - 2 * (h0 + RBH - 1)) * (1.0f / 128.0f) - RMARG;

  // +1 float4 pad: stride 2064 B -> the 8 lists a wave reads start on banks
  // {0,4,...,28}; each b128 spans a disjoint bank quad -> conflict-free.
  __shared__ float4 cand[NCELL][CAPS + 1];
  __shared__ int cnts[NCELL];
  if (tid < NCELL) cnts[tid] = 0;
  __syncthreads();

  const float* Rp = cams.R[v];
  const float* Tp = cams.T[v];
  float R0 = Rp[0], R1 = Rp[1], R2 = Rp[2];
  float R3 = Rp[3], R4 = Rp[4], R5 = Rp[5];
  float R6 = Rp[6], R7 = Rp[7], R8 = Rp[8];
  float T0 = Tp[0], T1 = Tp[1], T2 = Tp[2];

  // ---- phase 1: 10 vec4 loads up front, transform 8 pts, bin to sub-cells ----
  float4 A[2][3], C0[2], C1[2];
#pragma unroll
  for (int k = 0; k < 2; k++) {
    int g = k * 512 + tid;             // point-group (4 pts per group)
    A[k][0] = pcd4[3 * g + 0];
    A[k][1] = pcd4[3 * g + 1];
    A[k][2] = pcd4[3 * g + 2];
    C0[k] = add0_4[g];
    C1[k] = add1_4[g];
  }

  // blocks 0,1 (view-0 corner regions, light phase 2) emit the colors output
  if (b < 2) {
    int g = b * 512 + tid;
    float4 s;
    s.x = sigmoidf_fast(C0[b].x + C1[b].x);
    s.y = sigmoidf_fast(C0[b].y + C1[b].y);
    s.z = sigmoidf_fast(C0[b].z + C1[b].z);
    s.w = sigmoidf_fast(C0[b].w + C1[b].w);
    out_colors4[g] = s;
  }

#pragma unroll
  for (int k = 0; k < 2; k++) {
    float f[12] = {A[k][0].x, A[k][0].y, A[k][0].z, A[k][0].w,
                   A[k][1].x, A[k][1].y, A[k][1].z, A[k][1].w,
                   A[k][2].x, A[k][2].y, A[k][2].z, A[k][2].w};
    float sc[4] = {sigmoidf_fast(C0[k].x + C1[k].x),
                   sigmoidf_fast(C0[k].y + C1[k].y),
                   sigmoidf_fast(C0[k].z + C1[k].z),
                   sigmoidf_fast(C0[k].w + C1[k].w)};
#pragma unroll
    for (int j = 0; j < 4; j++) {
      float p0 = f[3 * j + 0], p1 = f[3 * j + 1], p2 = f[3 * j + 2];
      float px = p0 * R0 + p1 * R3 + p2 * R6 + T0;
      float py = p0 * R1 + p1 * R4 + p2 * R7 + T1;
      float pz = p0 * R2 + p1 * R5 + p2 * R8 + T2;
      if (pz > 0.01f && pz < 100.0f &&
          px > xlo && px < xhi && py > ylo && py < yhi) {
        // continuous local pixel span (w = (127-128*px)/2)
        float lwlo = (127.0f - 128.0f * (px + RMARG)) * 0.5f - (float)w0;
        float lwhi = (127.0f - 128.0f * (px - RMARG)) * 0.5f - (float)w0;
        float lhlo = (127.0f - 128.0f * (py + RMARG)) * 0.5f - (float)h0;
        float lhhi = (127.0f - 128.0f * (py - RMARG)) * 0.5f - (float)h0;
        int cxlo = (int)fmaxf(0.0f, floorf(lwlo * 0.25f));
        int cxhi = (int)fminf((float)(NCX - 1), floorf(lwhi * 0.25f));
        int cylo = (int)fmaxf(0.0f, floorf(lhlo * 0.25f));
        int cyhi = (int)fminf((float)(NCY - 1), floorf(lhhi * 0.25f));
        float4 payload = make_float4(px, py, pz, sc[j]);
        for (int cy = cylo; cy <= cyhi; cy++)
          for (int cx = cxlo; cx <= cxhi; cx++) {
            int li = cy * NCX + cx;
            int idx = atomicAdd(&cnts[li], 1);
            if (idx < CAPS) cand[li][idx] = payload;
          }
      }
    }
  }
  __syncthreads();

  // ---- phase 2: scan own 4x4-px cell's list (false positives re-tested) ----
  int li = (row >> 2) * NCX + (col >> 2);
  int n = cnts[li];
  if (n > CAPS) n = CAPS;
  const float4* list = cand[li];

  float zk[KTOP], wk[KTOP], ck[KTOP];
#pragma unroll
  for (int k = 0; k < KTOP; k++) { zk[k] = 1e30f; wk[k] = 0.0f; ck[k] = 0.0f; }

  int j = 0;
  for (; j + 8 <= n; j += 8) {
    float4 P0 = list[j + 0], P1 = list[j + 1], P2 = list[j + 2], P3 = list[j + 3];
    float4 P4 = list[j + 4], P5 = list[j + 5], P6 = list[j + 6], P7 = list[j + 7];
    process_cand(P0, xf, yf, zk, wk, ck);
    process_cand(P1, xf, yf, zk, wk, ck);
    process_cand(P2, xf, yf, zk, wk, ck);
    process_cand(P3, xf, yf, zk, wk, ck);
    process_cand(P4, xf, yf, zk, wk, ck);
    process_cand(P5, xf, yf, zk, wk, ck);
    process_cand(P6, xf, yf, zk, wk, ck);
    process_cand(P7, xf, yf, zk, wk, ck);
  }
  for (; j < n; j++) {
    float4 P = list[j];
    process_cand(P, xf, yf, zk, wk, ck);
  }

  // front-to-back alpha composite; empty slots w=0 are no-ops (matches ref)
  float acc = 0.0f, pre = 1.0f;
#pragma unroll
  for (int k = 0; k < KTOP; k++) {
    acc += wk[k] * pre * ck[k];
    pre *= (1.0f - wk[k]);
  }

  int base = v * (SDIM * SDIM * 3) + (h * SDIM + w) * 3;
  out[base + 0] = acc;
  out[base + 1] = acc;
  out[base + 2] = acc;
}

// ---------------- host: camera R,T from compile-time constants ----------------
static void compute_cams(CamParams* cp) {
  const double views[NV] = {45.0, 90.0, 135.0, 225.0, 270.0, 315.0};
  const double deg = M_PI / 180.0;
  const double elev = 15.0 * deg;
  const double dist = 1.5;
  for (int v = 0; v < NV; v++) {
    double az = views[v] * deg;
    double C[3] = {dist * cos(elev) * sin(az), dist * sin(elev),
                   dist * cos(elev) * cos(az)};
    double n = sqrt(C[0] * C[0] + C[1] * C[1] + C[2] * C[2]);
    double z[3] = {-C[0] / n, -C[1] / n, -C[2] / n};
    double up[3] = {0.0, 1.0, 0.0};
    double x[3] = {up[1] * z[2] - up[2] * z[1],
                   up[2] * z[0] - up[0] * z[2],
                   up[0] * z[1] - up[1] * z[0]};
    double nx = sqrt(x[0] * x[0] + x[1] * x[1] + x[2] * x[2]);
    x[0] /= nx; x[1] /= nx; x[2] /= nx;
    double y[3] = {z[1] * x[2] - z[2] * x[1],
                   z[2] * x[0] - z[0] * x[2],
                   z[0] * x[1] - z[1] * x[0]};
    double ny = sqrt(y[0] * y[0] + y[1] * y[1] + y[2] * y[2]);
    y[0] /= ny; y[1] /= ny; y[2] /= ny;
    double Rm[3][3];  // columns x, y, z
    for (int j = 0; j < 3; j++) { Rm[j][0] = x[j]; Rm[j][1] = y[j]; Rm[j][2] = z[j]; }
    for (int j = 0; j < 3; j++)
      for (int i = 0; i < 3; i++)
        cp->R[v][j * 3 + i] = (float)Rm[j][i];
    for (int i = 0; i < 3; i++)
      cp->T[v][i] = (float)(-(C[0] * Rm[0][i] + C[1] * Rm[1][i] + C[2] * Rm[2][i]));
  }
}

extern "C" void kernel_launch(void* const* d_in, const int* in_sizes, int n_in,
                              void* d_out, int out_size, void* d_ws, size_t ws_size,
                              hipStream_t stream) {
  CamParams cp;
  compute_cams(&cp);

  // Identify inputs by size (robust to ordering): pcd is the unique 3*NPTS
  // array; the two NPTS arrays are symmetric addends (init_colors + displace).
  const float* pcd = nullptr;
  const float* adds[2] = {nullptr, nullptr};
  int na = 0;
  for (int i = 0; i < n_in; i++) {
    if (in_sizes[i] == 3 * NPTS) pcd = (const float*)d_in[i];
    else if (na < 2) adds[na++] = (const float*)d_in[i];
  }
  if (!pcd || na < 2) { pcd = (const float*)d_in[0];
                        adds[0] = (const float*)d_in[1];
                        adds[1] = (const float*)d_in[2]; }

  float* out = (float*)d_out;
  float4* out_colors4 = (float4*)(out + IMG_ELEMS);   // byte offset %16 == 0

  fused_render_kernel<<<NBLK, 512, 0, stream>>>(
      (const float4*)pcd, (const float4*)adds[0], (const float4*)adds[1],
      out, out_colors4, cp);
}